// Round 8
// baseline (219.541 us; speedup 1.0000x reference)
//
#include <hip/hip_runtime.h>
#include <hip/hip_bf16.h>

typedef __attribute__((ext_vector_type(8))) short short8;     // 8 bf16 (4 VGPRs)
typedef __attribute__((ext_vector_type(4))) float f32x4;      // MFMA C/D
typedef __attribute__((ext_vector_type(8))) _Float16 half8;   // 8 fp16 (16B)

#define L_SEQ 4096
#define DM    1024
#define DA    128
#define AZ    16     // attn z-split (block-level partials)

// ws byte offsets (16B-aligned)
#define OFF_QB  786432      // after WTf (3*32*8*64 frags * 16B = 768 KB)
#define OFF_KF  1835008     // after qb (1 MB)
#define OFF_VF  2883584     // after kf (1 MB)
#define OFF_OA  4063232     // after vf (1 MB): OA (fp16) 16.78 MB, then lA 256 KB
#define OA_BYTES ((size_t)AZ * L_SEQ * DA * 2)
#define LA_BYTES ((size_t)AZ * L_SEQ * 4)
#define OFF_CNT (OFF_OA + OA_BYTES + LA_BYTES)   // 32 int counters

// fp32 -> bf16 round-to-nearest-even
__device__ __forceinline__ short f2bf(float f) {
    union { float f; unsigned u; } v; v.f = f;
    unsigned u = v.u;
    u += 0x7FFFu + ((u >> 16) & 1u);
    return (short)(u >> 16);
}

// packed fp32x2 -> bf16x2 (RNE), single VALU op
__device__ __forceinline__ unsigned cvt_pk_bf16(float lo, float hi) {
    unsigned r;
    asm("v_cvt_pk_bf16_f32 %0, %1, %2" : "=v"(r) : "v"(lo), "v"(hi));
    return r;
}

// async global->LDS, 16B per lane: dest = wave-uniform lds base + lane*16
typedef const __attribute__((address_space(1))) void g_void_t;
typedef __attribute__((address_space(3))) void l_void_t;
__device__ __forceinline__ void g2lds16(const void* g, void* l) {
    __builtin_amdgcn_global_load_lds((g_void_t*)g, (l_void_t*)l, 16, 0, 0);
}

// ---------------------------------------------------------------------------
// Kernel 0: W -> fragment-major bf16.  WTf frag (m, kstep, nt, lane):
//   elem j = W[kstep*32 + quad*8 + j][nt*16 + l16].   grid (32,3), block 256.
// Also zeroes the 32 per-qx merge counters (block (0,0)) — ws is poisoned
// each iteration; kernel-boundary coherence makes the zeros visible to attn.
// ---------------------------------------------------------------------------
__global__ __launch_bounds__(256) void prep_w_kernel(
    const float* __restrict__ Wq, const float* __restrict__ Wk,
    const float* __restrict__ Wv, short8* __restrict__ WTf,
    int* __restrict__ cnt)
{
    const int m = blockIdx.y, kidx = blockIdx.x;
    const int t = threadIdx.x;
    if (m == 0 && kidx == 0 && t < 32) cnt[t] = 0;
    const float* __restrict__ W = (m == 0) ? Wq : (m == 1) ? Wk : Wv;
    __shared__ __align__(16) float Ws[32 * 132];
#pragma unroll
    for (int i = 0; i < 4; i++) {
        const int u = i * 256 + t;
        const int kk = u >> 5, n4 = (u & 31) * 4;
        *(f32x4*)&Ws[kk * 132 + n4] = *(const f32x4*)&W[(size_t)(kidx * 32 + kk) * DA + n4];
    }
    __syncthreads();
#pragma unroll
    for (int i = 0; i < 2; i++) {
        const int u = i * 256 + t;
        const int nt = u >> 6, lane = u & 63, l16 = lane & 15, quad = lane >> 4;
        short8 fr;
#pragma unroll
        for (int j = 0; j < 8; j++)
            fr[j] = f2bf(Ws[(quad * 8 + j) * 132 + nt * 16 + l16]);
        WTf[((size_t)(m * 32 + kidx) * 8 + nt) * 64 + lane] = fr;
    }
}

// ---------------------------------------------------------------------------
// Kernel 1: fused QKV.  grid (128, 2), block 256.  by==0: q from x; by==1:
// k AND v from z (z read once).  Block owns 32 rows x full K=1024, BK=64
// (16 dbuf iterations).  Wave -> (mtile = w>>1, nhalf = w&1).  Epilogue
// writes FINAL outputs; q is PRESCALED by (1/sqrt(128))*log2(e) so attn can
// use exp2 with no per-element multiply.  k/v relaid to granule fragment
// layouts via LDS transpose (reusing staging buffer).
//   kf granule kg=z>>5: frag(kg,ks,nth,lane) elem j = k[kg*32+nth*16+l16][ks*32+quad*8+j]
//   vf granule vg=z>>5: frag(vg,nt,lane)     elem j = v[vg*32+quad*8+j][nt*16+l16]
//     (ones column for the row-sum trick is a constant reg frag in attn)
// ---------------------------------------------------------------------------
__global__ __launch_bounds__(256, 1) void qkv_kernel(
    const float* __restrict__ x, const float* __restrict__ z,
    const char* __restrict__ WTraw,
    const float* __restrict__ bq, const float* __restrict__ bk,
    const float* __restrict__ bv,
    short* __restrict__ qb, short8* __restrict__ kf, short8* __restrict__ vf)
{
    __shared__ __align__(16) char smem[2][32768];

    const int t = threadIdx.x;
    const int wave = t >> 6, lane = t & 63;
    const int l16 = lane & 15, quad = lane >> 4;
    const int mtile = wave >> 1, nhalf = wave & 1;
    const int isKV = blockIdx.y;
    const int m1 = isKV ? 1 : 0;
    const int row0 = blockIdx.x * 32;
    const int nbytes = isKV ? 32768 : 16384;

    const float* __restrict__ Am = isKV ? z : x;
    const float* ap = Am + (size_t)(row0 + mtile * 16 + l16) * DM + quad * 8;

    f32x4 acc1[4], acc2[4];
#pragma unroll
    for (int i = 0; i < 4; i++) {
        acc1[i] = (f32x4){0.f, 0.f, 0.f, 0.f};
        acc2[i] = (f32x4){0.f, 0.f, 0.f, 0.f};
    }

    // stage W frags for BK=64 iteration it2 into smem[b]:
    //   [m1 kstep even 8K][m1 kstep odd 8K][(kv) Wv even 8K][Wv odd 8K]
    auto stage = [&](int it2, int b) {
        const char* base1 = WTraw + (size_t)(m1 * 32 + it2 * 2) * 8192;
        const char* base2 = WTraw + (size_t)(2 * 32 + it2 * 2) * 8192;
#pragma unroll
        for (int i = 0; i < 8; i++) {
            const int off = i * 4096 + wave * 1024;
            if (off < nbytes) {
                const char* src = (off < 16384) ? (base1 + off) : (base2 + (off - 16384));
                g2lds16(src + lane * 16, &smem[b][off]);
            }
        }
    };

    // A pipeline: 4 f32x4 per iteration (two 32-k substeps), prefetch depth 2
    f32x4 cur[4], nxt[4];
#pragma unroll
    for (int j = 0; j < 2; j++) {
        cur[j * 2]     = *(const f32x4*)(ap + j * 32);
        cur[j * 2 + 1] = *(const f32x4*)(ap + j * 32 + 4);
        nxt[j * 2]     = *(const f32x4*)(ap + 64 + j * 32);
        nxt[j * 2 + 1] = *(const f32x4*)(ap + 64 + j * 32 + 4);
    }

    stage(0, 0);
    __syncthreads();

#pragma unroll 1
    for (int it = 0; it < 16; it++) {
        const int b = it & 1;
        if (it + 1 < 16) stage(it + 1, b ^ 1);

        const int ipf = (it + 2 < 16) ? it + 2 : it;
        f32x4 fut[4];
#pragma unroll
        for (int j = 0; j < 2; j++) {
            fut[j * 2]     = *(const f32x4*)(ap + ipf * 64 + j * 32);
            fut[j * 2 + 1] = *(const f32x4*)(ap + ipf * 64 + j * 32 + 4);
        }

#pragma unroll
        for (int ss = 0; ss < 2; ss++) {
            short8 afr;
#pragma unroll
            for (int j = 0; j < 4; j++) {
                afr[j]     = f2bf(cur[ss * 2][j]);
                afr[4 + j] = f2bf(cur[ss * 2 + 1][j]);
            }
#pragma unroll
            for (int ntl = 0; ntl < 4; ntl++) {
                short8 bfr = *(const short8*)&smem[b][ss * 8192 + ((nhalf * 4 + ntl) * 64 + lane) * 16];
                acc1[ntl] = __builtin_amdgcn_mfma_f32_16x16x32_bf16(afr, bfr, acc1[ntl], 0, 0, 0);
            }
            if (isKV) {
#pragma unroll
                for (int ntl = 0; ntl < 4; ntl++) {
                    short8 bfr = *(const short8*)&smem[b][16384 + ss * 8192 + ((nhalf * 4 + ntl) * 64 + lane) * 16];
                    acc2[ntl] = __builtin_amdgcn_mfma_f32_16x16x32_bf16(afr, bfr, acc2[ntl], 0, 0, 0);
                }
            }
        }
        __syncthreads();
#pragma unroll
        for (int j = 0; j < 4; j++) { cur[j] = nxt[j]; nxt[j] = fut[j]; }
    }

    // ---- epilogue.  C layout: row = mtile*16 + quad*4 + r, col = nhalf*64 + ntl*16 + l16
    if (!isKV) {
        const float CL2E = 0.1275187669712930f;   // (1/sqrt(128)) * log2(e)
#pragma unroll
        for (int ntl = 0; ntl < 4; ntl++) {
            const int col = nhalf * 64 + ntl * 16 + l16;
            const float bb = bq[col];
#pragma unroll
            for (int r = 0; r < 4; r++)
                qb[(size_t)(row0 + mtile * 16 + quad * 4 + r) * DA + col] =
                    f2bf((acc1[ntl][r] + bb) * CL2E);
        }
        return;
    }

    // k/v: C-frags -> LDS tiles [32][132] (k at smem 0, v at smem +16384)
    short* kT = (short*)&smem[0][0];
    short* vT = (short*)&smem[0][16384];
#pragma unroll
    for (int ntl = 0; ntl < 4; ntl++) {
        const int col = nhalf * 64 + ntl * 16 + l16;
        const float bbk = bk[col], bbv = bv[col];
#pragma unroll
        for (int r = 0; r < 4; r++) {
            const int rl = mtile * 16 + quad * 4 + r;
            kT[rl * 132 + col] = f2bf(acc1[ntl][r] + bbk);
            vT[rl * 132 + col] = f2bf(acc2[ntl][r] + bbv);
        }
    }
    __syncthreads();

    const int kg = blockIdx.x;   // this block's 32 rows = one granule
    // kf: 512 frags
#pragma unroll
    for (int i = 0; i < 2; i++) {
        const int f = i * 256 + t;
        const int ks = f >> 7, nth = (f >> 6) & 1, ln = f & 63;
        const int lf = ln & 15, qf = ln >> 4;
        short8 fr;
#pragma unroll
        for (int j = 0; j < 8; j++)
            fr[j] = kT[(nth * 16 + lf) * 132 + ks * 32 + qf * 8 + j];
        kf[((size_t)(kg * 4 + ks) * 2 + nth) * 64 + ln] = fr;
    }
    // vf: 512 frags (ones tile removed — constant in attn)
#pragma unroll
    for (int i = 0; i < 2; i++) {
        const int f = i * 256 + t;
        const int nt = f >> 6, ln = f & 63;
        const int lf = ln & 15, qf = ln >> 4;
        short8 fr;
#pragma unroll
        for (int j = 0; j < 8; j++)
            fr[j] = vT[(qf * 8 + j) * 132 + nt * 16 + lf];
        vf[((size_t)kg * 8 + nt) * 64 + ln] = fr;
    }
}

// ---------------------------------------------------------------------------
// Kernel 2: flash attention (max-free softmax) + FUSED MERGE.
// grid (32, AZ=16), block 256 (4 waves), 2 blocks/CU.  Wave owns 32 q-rows
// (2 m-tiles).  K via LDS double-buffer; V direct global->regs (L1 absorbs
// 4-wave duplication).  Swapped QK^T + permlane32/16 swaps keep P entirely
// in registers (see round-6/7 derivation).  s_setprio(1) wraps both MFMA
// clusters (T5).  After writing its OA/lA partial, each block release-fences
// and bumps cnt[qx] (device-scope atomic); the 16th block for a qx acquires
// and merges all AZ partials for its 128 rows -> out.  No merge kernel.
// ---------------------------------------------------------------------------
__global__ __launch_bounds__(256, 2) void attn_kernel(
    const short* __restrict__ qb, const char* __restrict__ kfg,
    const char* __restrict__ vfg, _Float16* __restrict__ OA,
    float* __restrict__ lA, int* __restrict__ cnt, float* __restrict__ out)
{
    __shared__ __align__(16) char kv[2][8192];        // [buf][kf granule]
    __shared__ int isLast;

    const int t    = threadIdx.x;
    const int wave = t >> 6;
    const int lane = t & 63;
    const int l16  = lane & 15;
    const int quad = lane >> 4;
    const int qr0  = blockIdx.x * 128;
    const int g0   = blockIdx.y * 8;    // first z-granule (32 rows each)

    auto stage = [&](int g, int b) {
        const char* kb_ = kfg + (size_t)(g0 + g) * 8192 + wave * 2048;
        g2lds16(kb_ + lane * 16,        &kv[b][wave * 2048]);
        g2lds16(kb_ + 1024 + lane * 16, &kv[b][wave * 2048 + 1024]);
    };

    stage(0, 0);

    // q A-fragments direct from global (once; overlaps staging). 2 m-tiles.
    short8 af[2][4];
#pragma unroll
    for (int mt = 0; mt < 2; mt++) {
        const short* qrow = qb + (size_t)(qr0 + wave * 32 + mt * 16 + l16) * DA + quad * 8;
#pragma unroll
        for (int ks = 0; ks < 4; ks++)
            af[mt][ks] = *(const short8*)(qrow + ks * 32);
    }

    // constant ones B-frag (row-sum column): B[0][k] = 1
    short8 bones;
#pragma unroll
    for (int j = 0; j < 8; j++) bones[j] = (l16 == 0) ? (short)0x3F80 : (short)0;

    f32x4 O[2][9];
#pragma unroll
    for (int mt = 0; mt < 2; mt++)
#pragma unroll
        for (int i = 0; i < 9; i++) O[mt][i] = (f32x4){0.f, 0.f, 0.f, 0.f};

    __syncthreads();   // buf0 ready

#pragma unroll 1
    for (int g = 0; g < 8; g++) {
        const int b = g & 1;
        if (g + 1 < 8) stage(g + 1, b ^ 1);   // async; drains at end-of-iter barrier

        // ---- V(g) direct global->regs (issued early; consumed after softmax) ----
        const short8* vgp = (const short8*)(vfg + (size_t)(g0 + g) * 8192);
        short8 b2v[8];
#pragma unroll
        for (int nt = 0; nt < 8; nt++)
            b2v[nt] = vgp[nt * 64 + lane];

        const char* kb_ = &kv[b][0];

        // ---- S^T = k @ q^T over this 32-z granule (k-frag shared by both mt) ----
        f32x4 st[2][2];
#pragma unroll
        for (int zh = 0; zh < 2; zh++)
#pragma unroll
            for (int mt = 0; mt < 2; mt++) st[zh][mt] = (f32x4){0.f, 0.f, 0.f, 0.f};
        __builtin_amdgcn_s_setprio(1);
#pragma unroll
        for (int ks = 0; ks < 4; ks++)
#pragma unroll
            for (int zh = 0; zh < 2; zh++) {
                const short8 kfr = *(const short8*)(kb_ + ((ks * 2 + zh) * 64 + lane) * 16);
                st[zh][0] = __builtin_amdgcn_mfma_f32_16x16x32_bf16(kfr, af[0][ks], st[zh][0], 0, 0, 0);
                st[zh][1] = __builtin_amdgcn_mfma_f32_16x16x32_bf16(kfr, af[1][ks], st[zh][1], 0, 0, 0);
            }
        __builtin_amdgcn_s_setprio(0);

        // ---- in-register softmax -> PV A-frags (2 p32 + 2 p16 swaps per mt) ----
        short8 a2[2];
#pragma unroll
        for (int mt = 0; mt < 2; mt++) {
            unsigned x0 = cvt_pk_bf16(exp2f(st[0][mt][0]), exp2f(st[0][mt][1]));
            unsigned x1 = cvt_pk_bf16(exp2f(st[0][mt][2]), exp2f(st[0][mt][3]));
            unsigned y0 = cvt_pk_bf16(exp2f(st[1][mt][0]), exp2f(st[1][mt][1]));
            unsigned y1 = cvt_pk_bf16(exp2f(st[1][mt][2]), exp2f(st[1][mt][3]));
            asm volatile("v_permlane32_swap_b32 %0, %1" : "+v"(x0), "+v"(y0));
            asm volatile("v_permlane32_swap_b32 %0, %1" : "+v"(x1), "+v"(y1));
            asm volatile("v_permlane16_swap_b32 %0, %1" : "+v"(x0), "+v"(y0));
            asm volatile("v_permlane16_swap_b32 %0, %1" : "+v"(x1), "+v"(y1));
            union { short8 s; unsigned u[4]; } pa;
            pa.u[0] = x0;
            pa.u[1] = x1;
            pa.u[2] = y0;
            pa.u[3] = y1;
            a2[mt] = pa.s;
        }

        // ---- O += P @ [V | 1] (K=32, all operands in registers) ----
        __builtin_amdgcn_s_setprio(1);
#pragma unroll
        for (int nt = 0; nt < 8; nt++) {
            O[0][nt] = __builtin_amdgcn_mfma_f32_16x16x32_bf16(a2[0], b2v[nt], O[0][nt], 0, 0, 0);
            O[1][nt] = __builtin_amdgcn_mfma_f32_16x16x32_bf16(a2[1], b2v[nt], O[1][nt], 0, 0, 0);
        }
        O[0][8] = __builtin_amdgcn_mfma_f32_16x16x32_bf16(a2[0], bones, O[0][8], 0, 0, 0);
        O[1][8] = __builtin_amdgcn_mfma_f32_16x16x32_bf16(a2[1], bones, O[1][8], 0, 0, 0);
        __builtin_amdgcn_s_setprio(0);
        __syncthreads();   // staging for g+1 drained; all waves done with K buf b
    }

    // ---- per-wave partial -> global fp16 (rows wave-exclusive); l stays fp32 ----
    const int rw = qr0 + wave * 32;
    _Float16* Ob = OA + (size_t)blockIdx.y * L_SEQ * DA;
#pragma unroll
    for (int mt = 0; mt < 2; mt++)
#pragma unroll
        for (int nt = 0; nt < 8; nt++)
#pragma unroll
            for (int r = 0; r < 4; r++)
                Ob[(size_t)(rw + mt * 16 + quad * 4 + r) * DA + nt * 16 + l16] =
                    (_Float16)O[mt][nt][r];
    if (l16 == 0) {
        float* lb = lA + (size_t)blockIdx.y * L_SEQ;
#pragma unroll
        for (int mt = 0; mt < 2; mt++)
#pragma unroll
            for (int r = 0; r < 4; r++)
                lb[rw + mt * 16 + quad * 4 + r] = O[mt][8][r];
    }

    // ---- last-block-per-qx merges the AZ partials for its 128 rows ----
    __threadfence();            // release: each thread's OA/lA writes -> agent scope
    __syncthreads();            // all threads' fences done before the atomic
    if (t == 0)
        isLast = (atomicAdd(&cnt[blockIdx.x], 1) == AZ - 1) ? 1 : 0;
    __syncthreads();
    if (isLast) {
        __threadfence();        // acquire: invalidate stale lines before reading peers
        const int rowb = t >> 4;         // 0..15
        const int cg   = (t & 15) * 8;   // col group
#pragma unroll 1
        for (int i = 0; i < 8; i++) {
            const int row = qr0 + i * 16 + rowb;
            float acc[8];
#pragma unroll
            for (int j = 0; j < 8; j++) acc[j] = 0.f;
            float lsum = 0.f;
#pragma unroll 1
            for (int zz = 0; zz < AZ; zz++) {
                const half8 v = *(const half8*)&OA[((size_t)zz * L_SEQ + row) * DA + cg];
#pragma unroll
                for (int j = 0; j < 8; j++) acc[j] += (float)v[j];
                lsum += lA[(size_t)zz * L_SEQ + row];
            }
            const float inv = 1.f / lsum;
            f32x4 o0, o1;
#pragma unroll
            for (int j = 0; j < 4; j++) { o0[j] = acc[j] * inv; o1[j] = acc[4 + j] * inv; }
            f32x4* dst = (f32x4*)&out[(size_t)row * DA + cg];
            dst[0] = o0;
            dst[1] = o1;
        }
    }
}

// ---------------------------------------------------------------------------
extern "C" void kernel_launch(void* const* d_in, const int* in_sizes, int n_in,
                              void* d_out, int out_size, void* d_ws, size_t ws_size,
                              hipStream_t stream) {
    (void)in_sizes; (void)n_in; (void)out_size; (void)ws_size;
    const float* x  = (const float*)d_in[0];
    const float* z  = (const float*)d_in[1];
    const float* Wq = (const float*)d_in[2];
    const float* bq = (const float*)d_in[3];
    const float* Wk = (const float*)d_in[4];
    const float* bk = (const float*)d_in[5];
    const float* Wv = (const float*)d_in[6];
    const float* bv = (const float*)d_in[7];
    float* out = (float*)d_out;

    short8*   WTf = (short8*)d_ws;
    short*    qb  = (short*)((char*)d_ws + OFF_QB);
    short8*   kf  = (short8*)((char*)d_ws + OFF_KF);
    short8*   vf  = (short8*)((char*)d_ws + OFF_VF);
    _Float16* OA  = (_Float16*)((char*)d_ws + OFF_OA);       // AZ*L*DA fp16
    float*    lA  = (float*)((char*)d_ws + OFF_OA + OA_BYTES);
    int*      cnt = (int*)((char*)d_ws + OFF_CNT);

    prep_w_kernel<<<dim3(32, 3), 256, 0, stream>>>(Wq, Wk, Wv, WTf, cnt);
    qkv_kernel<<<dim3(128, 2), 256, 0, stream>>>(x, z, (const char*)WTf,
                                                 bq, bk, bv, qb, kf, vf);
    attn_kernel<<<dim3(32, AZ), 256, 0, stream>>>(qb, (const char*)kf,
                                                  (const char*)vf, OA, lA,
                                                  cnt, out);
}

// Round 9
// 137.391 us; speedup vs baseline: 1.5979x; 1.5979x over previous
//
#include <hip/hip_runtime.h>
#include <hip/hip_bf16.h>

typedef __attribute__((ext_vector_type(8))) short short8;     // 8 bf16 (4 VGPRs)
typedef __attribute__((ext_vector_type(4))) float f32x4;      // MFMA C/D
typedef __attribute__((ext_vector_type(8))) _Float16 half8;   // 8 fp16 (16B)

#define L_SEQ 4096
#define DM    1024
#define DA    128
#define AZ    32     // attn z-split (block-level partials); 4 granules/block

// ws byte offsets (16B-aligned)
#define OFF_QB  786432      // after WTf (3*32*8*64 frags * 16B = 768 KB)
#define OFF_KF  1835008     // after qb (1 MB)
#define OFF_VF  2883584     // after kf (1 MB)
#define OFF_OA  4063232     // after vf (1 MB): OA (fp16) 33.55 MB, then lA 512 KB
#define OA_BYTES ((size_t)AZ * L_SEQ * DA * 2)

// fp32 -> bf16 round-to-nearest-even
__device__ __forceinline__ short f2bf(float f) {
    union { float f; unsigned u; } v; v.f = f;
    unsigned u = v.u;
    u += 0x7FFFu + ((u >> 16) & 1u);
    return (short)(u >> 16);
}

// packed fp32x2 -> bf16x2 (RNE), single VALU op
__device__ __forceinline__ unsigned cvt_pk_bf16(float lo, float hi) {
    unsigned r;
    asm("v_cvt_pk_bf16_f32 %0, %1, %2" : "=v"(r) : "v"(lo), "v"(hi));
    return r;
}

// async global->LDS, 16B per lane: dest = wave-uniform lds base + lane*16
typedef const __attribute__((address_space(1))) void g_void_t;
typedef __attribute__((address_space(3))) void l_void_t;
__device__ __forceinline__ void g2lds16(const void* g, void* l) {
    __builtin_amdgcn_global_load_lds((g_void_t*)g, (l_void_t*)l, 16, 0, 0);
}

// ---------------------------------------------------------------------------
// Kernel 0: W -> fragment-major bf16.  WTf frag (m, kstep, nt, lane):
//   elem j = W[kstep*32 + quad*8 + j][nt*16 + l16].   grid (32,3), block 256.
// ---------------------------------------------------------------------------
__global__ __launch_bounds__(256) void prep_w_kernel(
    const float* __restrict__ Wq, const float* __restrict__ Wk,
    const float* __restrict__ Wv, short8* __restrict__ WTf)
{
    const int m = blockIdx.y, kidx = blockIdx.x;
    const float* __restrict__ W = (m == 0) ? Wq : (m == 1) ? Wk : Wv;
    __shared__ __align__(16) float Ws[32 * 132];
    const int t = threadIdx.x;
#pragma unroll
    for (int i = 0; i < 4; i++) {
        const int u = i * 256 + t;
        const int kk = u >> 5, n4 = (u & 31) * 4;
        *(f32x4*)&Ws[kk * 132 + n4] = *(const f32x4*)&W[(size_t)(kidx * 32 + kk) * DA + n4];
    }
    __syncthreads();
#pragma unroll
    for (int i = 0; i < 2; i++) {
        const int u = i * 256 + t;
        const int nt = u >> 6, lane = u & 63, l16 = lane & 15, quad = lane >> 4;
        short8 fr;
#pragma unroll
        for (int j = 0; j < 8; j++)
            fr[j] = f2bf(Ws[(quad * 8 + j) * 132 + nt * 16 + l16]);
        WTf[((size_t)(m * 32 + kidx) * 8 + nt) * 64 + lane] = fr;
    }
}

// ---------------------------------------------------------------------------
// Kernel 1: fused QKV.  grid (128, 2), block 256.  by==0: q from x; by==1:
// k AND v from z (z read once).  Block owns 32 rows x full K=1024, BK=64
// (16 dbuf iterations).  Wave -> (mtile = w>>1, nhalf = w&1).  Epilogue
// writes FINAL outputs; q is PRESCALED by (1/sqrt(128))*log2(e) so attn can
// use exp2 with no per-element multiply.  k/v relaid to granule fragment
// layouts via LDS transpose (reusing staging buffer).
//   kf granule kg=z>>5: frag(kg,ks,nth,lane) elem j = k[kg*32+nth*16+l16][ks*32+quad*8+j]
//   vf granule vg=z>>5: frag(vg,nt,lane)     elem j = v[vg*32+quad*8+j][nt*16+l16]
//     (ones column for the row-sum trick is a constant reg frag in attn)
// ---------------------------------------------------------------------------
__global__ __launch_bounds__(256, 1) void qkv_kernel(
    const float* __restrict__ x, const float* __restrict__ z,
    const char* __restrict__ WTraw,
    const float* __restrict__ bq, const float* __restrict__ bk,
    const float* __restrict__ bv,
    short* __restrict__ qb, short8* __restrict__ kf, short8* __restrict__ vf)
{
    __shared__ __align__(16) char smem[2][32768];

    const int t = threadIdx.x;
    const int wave = t >> 6, lane = t & 63;
    const int l16 = lane & 15, quad = lane >> 4;
    const int mtile = wave >> 1, nhalf = wave & 1;
    const int isKV = blockIdx.y;
    const int m1 = isKV ? 1 : 0;
    const int row0 = blockIdx.x * 32;
    const int nbytes = isKV ? 32768 : 16384;

    const float* __restrict__ Am = isKV ? z : x;
    const float* ap = Am + (size_t)(row0 + mtile * 16 + l16) * DM + quad * 8;

    f32x4 acc1[4], acc2[4];
#pragma unroll
    for (int i = 0; i < 4; i++) {
        acc1[i] = (f32x4){0.f, 0.f, 0.f, 0.f};
        acc2[i] = (f32x4){0.f, 0.f, 0.f, 0.f};
    }

    // stage W frags for BK=64 iteration it2 into smem[b]:
    //   [m1 kstep even 8K][m1 kstep odd 8K][(kv) Wv even 8K][Wv odd 8K]
    auto stage = [&](int it2, int b) {
        const char* base1 = WTraw + (size_t)(m1 * 32 + it2 * 2) * 8192;
        const char* base2 = WTraw + (size_t)(2 * 32 + it2 * 2) * 8192;
#pragma unroll
        for (int i = 0; i < 8; i++) {
            const int off = i * 4096 + wave * 1024;
            if (off < nbytes) {
                const char* src = (off < 16384) ? (base1 + off) : (base2 + (off - 16384));
                g2lds16(src + lane * 16, &smem[b][off]);
            }
        }
    };

    // A pipeline: 4 f32x4 per iteration (two 32-k substeps), prefetch depth 2
    f32x4 cur[4], nxt[4];
#pragma unroll
    for (int j = 0; j < 2; j++) {
        cur[j * 2]     = *(const f32x4*)(ap + j * 32);
        cur[j * 2 + 1] = *(const f32x4*)(ap + j * 32 + 4);
        nxt[j * 2]     = *(const f32x4*)(ap + 64 + j * 32);
        nxt[j * 2 + 1] = *(const f32x4*)(ap + 64 + j * 32 + 4);
    }

    stage(0, 0);
    __syncthreads();

#pragma unroll 1
    for (int it = 0; it < 16; it++) {
        const int b = it & 1;
        if (it + 1 < 16) stage(it + 1, b ^ 1);

        const int ipf = (it + 2 < 16) ? it + 2 : it;
        f32x4 fut[4];
#pragma unroll
        for (int j = 0; j < 2; j++) {
            fut[j * 2]     = *(const f32x4*)(ap + ipf * 64 + j * 32);
            fut[j * 2 + 1] = *(const f32x4*)(ap + ipf * 64 + j * 32 + 4);
        }

#pragma unroll
        for (int ss = 0; ss < 2; ss++) {
            short8 afr;
#pragma unroll
            for (int j = 0; j < 4; j++) {
                afr[j]     = f2bf(cur[ss * 2][j]);
                afr[4 + j] = f2bf(cur[ss * 2 + 1][j]);
            }
#pragma unroll
            for (int ntl = 0; ntl < 4; ntl++) {
                short8 bfr = *(const short8*)&smem[b][ss * 8192 + ((nhalf * 4 + ntl) * 64 + lane) * 16];
                acc1[ntl] = __builtin_amdgcn_mfma_f32_16x16x32_bf16(afr, bfr, acc1[ntl], 0, 0, 0);
            }
            if (isKV) {
#pragma unroll
                for (int ntl = 0; ntl < 4; ntl++) {
                    short8 bfr = *(const short8*)&smem[b][16384 + ss * 8192 + ((nhalf * 4 + ntl) * 64 + lane) * 16];
                    acc2[ntl] = __builtin_amdgcn_mfma_f32_16x16x32_bf16(afr, bfr, acc2[ntl], 0, 0, 0);
                }
            }
        }
        __syncthreads();
#pragma unroll
        for (int j = 0; j < 4; j++) { cur[j] = nxt[j]; nxt[j] = fut[j]; }
    }

    // ---- epilogue.  C layout: row = mtile*16 + quad*4 + r, col = nhalf*64 + ntl*16 + l16
    if (!isKV) {
        const float CL2E = 0.1275187669712930f;   // (1/sqrt(128)) * log2(e)
#pragma unroll
        for (int ntl = 0; ntl < 4; ntl++) {
            const int col = nhalf * 64 + ntl * 16 + l16;
            const float bb = bq[col];
#pragma unroll
            for (int r = 0; r < 4; r++)
                qb[(size_t)(row0 + mtile * 16 + quad * 4 + r) * DA + col] =
                    f2bf((acc1[ntl][r] + bb) * CL2E);
        }
        return;
    }

    // k/v: C-frags -> LDS tiles [32][132] (k at smem 0, v at smem +16384)
    short* kT = (short*)&smem[0][0];
    short* vT = (short*)&smem[0][16384];
#pragma unroll
    for (int ntl = 0; ntl < 4; ntl++) {
        const int col = nhalf * 64 + ntl * 16 + l16;
        const float bbk = bk[col], bbv = bv[col];
#pragma unroll
        for (int r = 0; r < 4; r++) {
            const int rl = mtile * 16 + quad * 4 + r;
            kT[rl * 132 + col] = f2bf(acc1[ntl][r] + bbk);
            vT[rl * 132 + col] = f2bf(acc2[ntl][r] + bbv);
        }
    }
    __syncthreads();

    const int kg = blockIdx.x;   // this block's 32 rows = one granule
    // kf: 512 frags
#pragma unroll
    for (int i = 0; i < 2; i++) {
        const int f = i * 256 + t;
        const int ks = f >> 7, nth = (f >> 6) & 1, ln = f & 63;
        const int lf = ln & 15, qf = ln >> 4;
        short8 fr;
#pragma unroll
        for (int j = 0; j < 8; j++)
            fr[j] = kT[(nth * 16 + lf) * 132 + ks * 32 + qf * 8 + j];
        kf[((size_t)(kg * 4 + ks) * 2 + nth) * 64 + ln] = fr;
    }
    // vf: 512 frags (ones tile removed — constant in attn)
#pragma unroll
    for (int i = 0; i < 2; i++) {
        const int f = i * 256 + t;
        const int nt = f >> 6, ln = f & 63;
        const int lf = ln & 15, qf = ln >> 4;
        short8 fr;
#pragma unroll
        for (int j = 0; j < 8; j++)
            fr[j] = vT[(qf * 8 + j) * 132 + nt * 16 + lf];
        vf[((size_t)kg * 8 + nt) * 64 + ln] = fr;
    }
}

// ---------------------------------------------------------------------------
// Kernel 2: flash attention (max-free softmax).  grid (32, AZ=32), block 256
// (4 waves), 4 blocks/CU (grid 1024 = 4/CU; VGPR 92*16=... fits, LDS 67.6 KB).
// Wave owns 32 q-rows (2 m-tiles); block processes 4 z-granules.
// K via LDS double-buffer; V direct global->regs (L1 absorbs 4-wave dup).
// Swapped QK^T + permlane32/16 swaps keep P entirely in registers (round-6/7
// derivation).  s_setprio(1) wraps both MFMA clusters (T5, m191 +4-7%).
// NOTE (round-8 lesson): NO device-scope fences in the hot path — agent
// fences lower to full-L2 wb/inv on gfx950 and thrash every XCD.
// ---------------------------------------------------------------------------
__global__ __launch_bounds__(256, 2) void attn_kernel(
    const short* __restrict__ qb, const char* __restrict__ kfg,
    const char* __restrict__ vfg, _Float16* __restrict__ OA,
    float* __restrict__ lA)
{
    __shared__ __align__(16) char kv[2][8192];        // [buf][kf granule]

    const int t    = threadIdx.x;
    const int wave = t >> 6;
    const int lane = t & 63;
    const int l16  = lane & 15;
    const int quad = lane >> 4;
    const int qr0  = blockIdx.x * 128;
    const int g0   = blockIdx.y * 4;    // first z-granule (32 rows each)

    auto stage = [&](int g, int b) {
        const char* kb_ = kfg + (size_t)(g0 + g) * 8192 + wave * 2048;
        g2lds16(kb_ + lane * 16,        &kv[b][wave * 2048]);
        g2lds16(kb_ + 1024 + lane * 16, &kv[b][wave * 2048 + 1024]);
    };

    stage(0, 0);

    // q A-fragments direct from global (once; overlaps staging). 2 m-tiles.
    short8 af[2][4];
#pragma unroll
    for (int mt = 0; mt < 2; mt++) {
        const short* qrow = qb + (size_t)(qr0 + wave * 32 + mt * 16 + l16) * DA + quad * 8;
#pragma unroll
        for (int ks = 0; ks < 4; ks++)
            af[mt][ks] = *(const short8*)(qrow + ks * 32);
    }

    // constant ones B-frag (row-sum column): B[0][k] = 1
    short8 bones;
#pragma unroll
    for (int j = 0; j < 8; j++) bones[j] = (l16 == 0) ? (short)0x3F80 : (short)0;

    f32x4 O[2][9];
#pragma unroll
    for (int mt = 0; mt < 2; mt++)
#pragma unroll
        for (int i = 0; i < 9; i++) O[mt][i] = (f32x4){0.f, 0.f, 0.f, 0.f};

    __syncthreads();   // buf0 ready

#pragma unroll 1
    for (int g = 0; g < 4; g++) {
        const int b = g & 1;
        if (g + 1 < 4) stage(g + 1, b ^ 1);   // async; drains at end-of-iter barrier

        // ---- V(g) direct global->regs (issued early; consumed after softmax) ----
        const short8* vgp = (const short8*)(vfg + (size_t)(g0 + g) * 8192);
        short8 b2v[8];
#pragma unroll
        for (int nt = 0; nt < 8; nt++)
            b2v[nt] = vgp[nt * 64 + lane];

        const char* kb_ = &kv[b][0];

        // ---- S^T = k @ q^T over this 32-z granule (k-frag shared by both mt) ----
        f32x4 st[2][2];
#pragma unroll
        for (int zh = 0; zh < 2; zh++)
#pragma unroll
            for (int mt = 0; mt < 2; mt++) st[zh][mt] = (f32x4){0.f, 0.f, 0.f, 0.f};
        __builtin_amdgcn_s_setprio(1);
#pragma unroll
        for (int ks = 0; ks < 4; ks++)
#pragma unroll
            for (int zh = 0; zh < 2; zh++) {
                const short8 kfr = *(const short8*)(kb_ + ((ks * 2 + zh) * 64 + lane) * 16);
                st[zh][0] = __builtin_amdgcn_mfma_f32_16x16x32_bf16(kfr, af[0][ks], st[zh][0], 0, 0, 0);
                st[zh][1] = __builtin_amdgcn_mfma_f32_16x16x32_bf16(kfr, af[1][ks], st[zh][1], 0, 0, 0);
            }
        __builtin_amdgcn_s_setprio(0);

        // ---- in-register softmax -> PV A-frags (2 p32 + 2 p16 swaps per mt) ----
        short8 a2[2];
#pragma unroll
        for (int mt = 0; mt < 2; mt++) {
            unsigned x0 = cvt_pk_bf16(exp2f(st[0][mt][0]), exp2f(st[0][mt][1]));
            unsigned x1 = cvt_pk_bf16(exp2f(st[0][mt][2]), exp2f(st[0][mt][3]));
            unsigned y0 = cvt_pk_bf16(exp2f(st[1][mt][0]), exp2f(st[1][mt][1]));
            unsigned y1 = cvt_pk_bf16(exp2f(st[1][mt][2]), exp2f(st[1][mt][3]));
            asm volatile("v_permlane32_swap_b32 %0, %1" : "+v"(x0), "+v"(y0));
            asm volatile("v_permlane32_swap_b32 %0, %1" : "+v"(x1), "+v"(y1));
            asm volatile("v_permlane16_swap_b32 %0, %1" : "+v"(x0), "+v"(y0));
            asm volatile("v_permlane16_swap_b32 %0, %1" : "+v"(x1), "+v"(y1));
            union { short8 s; unsigned u[4]; } pa;
            pa.u[0] = x0;
            pa.u[1] = x1;
            pa.u[2] = y0;
            pa.u[3] = y1;
            a2[mt] = pa.s;
        }

        // ---- O += P @ [V | 1] (K=32, all operands in registers) ----
        __builtin_amdgcn_s_setprio(1);
#pragma unroll
        for (int nt = 0; nt < 8; nt++) {
            O[0][nt] = __builtin_amdgcn_mfma_f32_16x16x32_bf16(a2[0], b2v[nt], O[0][nt], 0, 0, 0);
            O[1][nt] = __builtin_amdgcn_mfma_f32_16x16x32_bf16(a2[1], b2v[nt], O[1][nt], 0, 0, 0);
        }
        O[0][8] = __builtin_amdgcn_mfma_f32_16x16x32_bf16(a2[0], bones, O[0][8], 0, 0, 0);
        O[1][8] = __builtin_amdgcn_mfma_f32_16x16x32_bf16(a2[1], bones, O[1][8], 0, 0, 0);
        __builtin_amdgcn_s_setprio(0);
        __syncthreads();   // staging for g+1 drained; all waves done with K buf b
    }

    // ---- per-wave partial -> global fp16 (rows wave-exclusive); l stays fp32 ----
    const int rw = qr0 + wave * 32;
    _Float16* Ob = OA + (size_t)blockIdx.y * L_SEQ * DA;
#pragma unroll
    for (int mt = 0; mt < 2; mt++)
#pragma unroll
        for (int nt = 0; nt < 8; nt++)
#pragma unroll
            for (int r = 0; r < 4; r++)
                Ob[(size_t)(rw + mt * 16 + quad * 4 + r) * DA + nt * 16 + l16] =
                    (_Float16)O[mt][nt][r];
    if (l16 == 0) {
        float* lb = lA + (size_t)blockIdx.y * L_SEQ;
#pragma unroll
        for (int mt = 0; mt < 2; mt++)
#pragma unroll
            for (int r = 0; r < 4; r++)
                lb[rw + mt * 16 + quad * 4 + r] = O[mt][8][r];
    }
}

// ---------------------------------------------------------------------------
// Kernel 3: merge AZ partials: out = sum(OA) / sum(lA).  grid 256, block 256.
// OA is fp16 (16B = 8 elems per lane-load), accumulate fp32.
// ---------------------------------------------------------------------------
__global__ __launch_bounds__(256) void merge_kernel(
    const _Float16* __restrict__ OA, const float* __restrict__ lA,
    float* __restrict__ out)
{
    const int t = threadIdx.x;
    const int row = blockIdx.x * 16 + (t >> 4);
    const int cg = (t & 15) * 8;

    float acc[8];
#pragma unroll
    for (int j = 0; j < 8; j++) acc[j] = 0.f;
    float lsum = 0.f;
#pragma unroll 1
    for (int zz = 0; zz < AZ; zz++) {
        const half8 v = *(const half8*)&OA[((size_t)zz * L_SEQ + row) * DA + cg];
#pragma unroll
        for (int j = 0; j < 8; j++) acc[j] += (float)v[j];
        lsum += lA[(size_t)zz * L_SEQ + row];
    }
    const float inv = 1.f / lsum;
    f32x4 o0, o1;
#pragma unroll
    for (int j = 0; j < 4; j++) { o0[j] = acc[j] * inv; o1[j] = acc[4 + j] * inv; }
    f32x4* dst = (f32x4*)&out[(size_t)row * DA + cg];
    dst[0] = o0;
    dst[1] = o1;
}

// ---------------------------------------------------------------------------
extern "C" void kernel_launch(void* const* d_in, const int* in_sizes, int n_in,
                              void* d_out, int out_size, void* d_ws, size_t ws_size,
                              hipStream_t stream) {
    (void)in_sizes; (void)n_in; (void)out_size; (void)ws_size;
    const float* x  = (const float*)d_in[0];
    const float* z  = (const float*)d_in[1];
    const float* Wq = (const float*)d_in[2];
    const float* bq = (const float*)d_in[3];
    const float* Wk = (const float*)d_in[4];
    const float* bk = (const float*)d_in[5];
    const float* Wv = (const float*)d_in[6];
    const float* bv = (const float*)d_in[7];
    float* out = (float*)d_out;

    short8*   WTf = (short8*)d_ws;
    short*    qb  = (short*)((char*)d_ws + OFF_QB);
    short8*   kf  = (short8*)((char*)d_ws + OFF_KF);
    short8*   vf  = (short8*)((char*)d_ws + OFF_VF);
    _Float16* OA  = (_Float16*)((char*)d_ws + OFF_OA);       // AZ*L*DA fp16
    float*    lA  = (float*)((char*)d_ws + OFF_OA + OA_BYTES);

    prep_w_kernel<<<dim3(32, 3), 256, 0, stream>>>(Wq, Wk, Wv, WTf);
    qkv_kernel<<<dim3(128, 2), 256, 0, stream>>>(x, z, (const char*)WTf,
                                                 bq, bk, bv, qb, kf, vf);
    attn_kernel<<<dim3(32, AZ), 256, 0, stream>>>(qb, (const char*)kf,
                                                  (const char*)vf, OA, lA);
    merge_kernel<<<256, 256, 0, stream>>>(OA, lA, out);
}

// Round 10
// 124.879 us; speedup vs baseline: 1.7580x; 1.1002x over previous
//
#include <hip/hip_runtime.h>
#include <hip/hip_bf16.h>

typedef __attribute__((ext_vector_type(8))) short short8;     // 8 bf16 (4 VGPRs)
typedef __attribute__((ext_vector_type(4))) float f32x4;      // MFMA C/D
typedef __attribute__((ext_vector_type(8))) _Float16 half8;   // 8 fp16 (16B)

#define L_SEQ 4096
#define DM    1024
#define DA    128
#define AZ    16     // attn z-split (block-level partials); 8 granules/block

// ws byte offsets (16B-aligned)
#define OFF_QB  786432      // after WTf (3*32*8*64 frags * 16B = 768 KB)
#define OFF_KF  1835008     // after qb (1 MB)
#define OFF_VF  2883584     // after kf (1 MB)
#define OFF_OA  4063232     // after vf (1 MB): OA (fp16) 16.78 MB, then lA 256 KB
#define OA_BYTES ((size_t)AZ * L_SEQ * DA * 2)

// fp32 -> bf16 round-to-nearest-even
__device__ __forceinline__ short f2bf(float f) {
    union { float f; unsigned u; } v; v.f = f;
    unsigned u = v.u;
    u += 0x7FFFu + ((u >> 16) & 1u);
    return (short)(u >> 16);
}

// packed fp32x2 -> bf16x2 (RNE), single VALU op
__device__ __forceinline__ unsigned cvt_pk_bf16(float lo, float hi) {
    unsigned r;
    asm("v_cvt_pk_bf16_f32 %0, %1, %2" : "=v"(r) : "v"(lo), "v"(hi));
    return r;
}

// async global->LDS, 16B per lane: dest = wave-uniform lds base + lane*16
typedef const __attribute__((address_space(1))) void g_void_t;
typedef __attribute__((address_space(3))) void l_void_t;
__device__ __forceinline__ void g2lds16(const void* g, void* l) {
    __builtin_amdgcn_global_load_lds((g_void_t*)g, (l_void_t*)l, 16, 0, 0);
}

// ---------------------------------------------------------------------------
// Kernel 0: W -> fragment-major bf16.  WTf frag (m, kstep, nt, lane):
//   elem j = W[kstep*32 + quad*8 + j][nt*16 + l16].   grid (32,3), block 256.
// ---------------------------------------------------------------------------
__global__ __launch_bounds__(256) void prep_w_kernel(
    const float* __restrict__ Wq, const float* __restrict__ Wk,
    const float* __restrict__ Wv, short8* __restrict__ WTf)
{
    const int m = blockIdx.y, kidx = blockIdx.x;
    const float* __restrict__ W = (m == 0) ? Wq : (m == 1) ? Wk : Wv;
    __shared__ __align__(16) float Ws[32 * 132];
    const int t = threadIdx.x;
#pragma unroll
    for (int i = 0; i < 4; i++) {
        const int u = i * 256 + t;
        const int kk = u >> 5, n4 = (u & 31) * 4;
        *(f32x4*)&Ws[kk * 132 + n4] = *(const f32x4*)&W[(size_t)(kidx * 32 + kk) * DA + n4];
    }
    __syncthreads();
#pragma unroll
    for (int i = 0; i < 2; i++) {
        const int u = i * 256 + t;
        const int nt = u >> 6, lane = u & 63, l16 = lane & 15, quad = lane >> 4;
        short8 fr;
#pragma unroll
        for (int j = 0; j < 8; j++)
            fr[j] = f2bf(Ws[(quad * 8 + j) * 132 + nt * 16 + l16]);
        WTf[((size_t)(m * 32 + kidx) * 8 + nt) * 64 + lane] = fr;
    }
}

// ---------------------------------------------------------------------------
// Kernel 1: fused QKV.  grid (128, 2), block 256.  by==0: q from x; by==1:
// k AND v from z (z read once).  Block owns 32 rows x full K=1024, BK=64
// (16 dbuf iterations).  Wave -> (mtile = w>>1, nhalf = w&1).  Epilogue
// writes FINAL outputs; q is PRESCALED by (1/sqrt(128))*log2(e) so attn can
// use exp2 with no per-element multiply.  k/v relaid to granule fragment
// layouts via LDS transpose (reusing staging buffer).
//   kf granule kg=z>>5: frag(kg,ks,nth,lane) elem j = k[kg*32+nth*16+l16][ks*32+quad*8+j]
//   vf granule vg=z>>5: frag(vg,nt,lane)     elem j = v[vg*32+quad*8+j][nt*16+l16]
//     (ones column for the row-sum trick is a constant reg frag in attn)
// ---------------------------------------------------------------------------
__global__ __launch_bounds__(256, 1) void qkv_kernel(
    const float* __restrict__ x, const float* __restrict__ z,
    const char* __restrict__ WTraw,
    const float* __restrict__ bq, const float* __restrict__ bk,
    const float* __restrict__ bv,
    short* __restrict__ qb, short8* __restrict__ kf, short8* __restrict__ vf)
{
    __shared__ __align__(16) char smem[2][32768];

    const int t = threadIdx.x;
    const int wave = t >> 6, lane = t & 63;
    const int l16 = lane & 15, quad = lane >> 4;
    const int mtile = wave >> 1, nhalf = wave & 1;
    const int isKV = blockIdx.y;
    const int m1 = isKV ? 1 : 0;
    const int row0 = blockIdx.x * 32;
    const int nbytes = isKV ? 32768 : 16384;

    const float* __restrict__ Am = isKV ? z : x;
    const float* ap = Am + (size_t)(row0 + mtile * 16 + l16) * DM + quad * 8;

    f32x4 acc1[4], acc2[4];
#pragma unroll
    for (int i = 0; i < 4; i++) {
        acc1[i] = (f32x4){0.f, 0.f, 0.f, 0.f};
        acc2[i] = (f32x4){0.f, 0.f, 0.f, 0.f};
    }

    // stage W frags for BK=64 iteration it2 into smem[b]:
    //   [m1 kstep even 8K][m1 kstep odd 8K][(kv) Wv even 8K][Wv odd 8K]
    auto stage = [&](int it2, int b) {
        const char* base1 = WTraw + (size_t)(m1 * 32 + it2 * 2) * 8192;
        const char* base2 = WTraw + (size_t)(2 * 32 + it2 * 2) * 8192;
#pragma unroll
        for (int i = 0; i < 8; i++) {
            const int off = i * 4096 + wave * 1024;
            if (off < nbytes) {
                const char* src = (off < 16384) ? (base1 + off) : (base2 + (off - 16384));
                g2lds16(src + lane * 16, &smem[b][off]);
            }
        }
    };

    // A pipeline: 4 f32x4 per iteration (two 32-k substeps), prefetch depth 2
    f32x4 cur[4], nxt[4];
#pragma unroll
    for (int j = 0; j < 2; j++) {
        cur[j * 2]     = *(const f32x4*)(ap + j * 32);
        cur[j * 2 + 1] = *(const f32x4*)(ap + j * 32 + 4);
        nxt[j * 2]     = *(const f32x4*)(ap + 64 + j * 32);
        nxt[j * 2 + 1] = *(const f32x4*)(ap + 64 + j * 32 + 4);
    }

    stage(0, 0);
    __syncthreads();

#pragma unroll 1
    for (int it = 0; it < 16; it++) {
        const int b = it & 1;
        if (it + 1 < 16) stage(it + 1, b ^ 1);

        const int ipf = (it + 2 < 16) ? it + 2 : it;
        f32x4 fut[4];
#pragma unroll
        for (int j = 0; j < 2; j++) {
            fut[j * 2]     = *(const f32x4*)(ap + ipf * 64 + j * 32);
            fut[j * 2 + 1] = *(const f32x4*)(ap + ipf * 64 + j * 32 + 4);
        }

#pragma unroll
        for (int ss = 0; ss < 2; ss++) {
            short8 afr;
#pragma unroll
            for (int j = 0; j < 4; j++) {
                afr[j]     = f2bf(cur[ss * 2][j]);
                afr[4 + j] = f2bf(cur[ss * 2 + 1][j]);
            }
#pragma unroll
            for (int ntl = 0; ntl < 4; ntl++) {
                short8 bfr = *(const short8*)&smem[b][ss * 8192 + ((nhalf * 4 + ntl) * 64 + lane) * 16];
                acc1[ntl] = __builtin_amdgcn_mfma_f32_16x16x32_bf16(afr, bfr, acc1[ntl], 0, 0, 0);
            }
            if (isKV) {
#pragma unroll
                for (int ntl = 0; ntl < 4; ntl++) {
                    short8 bfr = *(const short8*)&smem[b][16384 + ss * 8192 + ((nhalf * 4 + ntl) * 64 + lane) * 16];
                    acc2[ntl] = __builtin_amdgcn_mfma_f32_16x16x32_bf16(afr, bfr, acc2[ntl], 0, 0, 0);
                }
            }
        }
        __syncthreads();
#pragma unroll
        for (int j = 0; j < 4; j++) { cur[j] = nxt[j]; nxt[j] = fut[j]; }
    }

    // ---- epilogue.  C layout: row = mtile*16 + quad*4 + r, col = nhalf*64 + ntl*16 + l16
    if (!isKV) {
        const float CL2E = 0.1275187669712930f;   // (1/sqrt(128)) * log2(e)
#pragma unroll
        for (int ntl = 0; ntl < 4; ntl++) {
            const int col = nhalf * 64 + ntl * 16 + l16;
            const float bb = bq[col];
#pragma unroll
            for (int r = 0; r < 4; r++)
                qb[(size_t)(row0 + mtile * 16 + quad * 4 + r) * DA + col] =
                    f2bf((acc1[ntl][r] + bb) * CL2E);
        }
        return;
    }

    // k/v: C-frags -> LDS tiles [32][132] (k at smem 0, v at smem +16384)
    short* kT = (short*)&smem[0][0];
    short* vT = (short*)&smem[0][16384];
#pragma unroll
    for (int ntl = 0; ntl < 4; ntl++) {
        const int col = nhalf * 64 + ntl * 16 + l16;
        const float bbk = bk[col], bbv = bv[col];
#pragma unroll
        for (int r = 0; r < 4; r++) {
            const int rl = mtile * 16 + quad * 4 + r;
            kT[rl * 132 + col] = f2bf(acc1[ntl][r] + bbk);
            vT[rl * 132 + col] = f2bf(acc2[ntl][r] + bbv);
        }
    }
    __syncthreads();

    const int kg = blockIdx.x;   // this block's 32 rows = one granule
    // kf: 512 frags
#pragma unroll
    for (int i = 0; i < 2; i++) {
        const int f = i * 256 + t;
        const int ks = f >> 7, nth = (f >> 6) & 1, ln = f & 63;
        const int lf = ln & 15, qf = ln >> 4;
        short8 fr;
#pragma unroll
        for (int j = 0; j < 8; j++)
            fr[j] = kT[(nth * 16 + lf) * 132 + ks * 32 + qf * 8 + j];
        kf[((size_t)(kg * 4 + ks) * 2 + nth) * 64 + ln] = fr;
    }
    // vf: 512 frags (ones tile removed — constant in attn)
#pragma unroll
    for (int i = 0; i < 2; i++) {
        const int f = i * 256 + t;
        const int nt = f >> 6, ln = f & 63;
        const int lf = ln & 15, qf = ln >> 4;
        short8 fr;
#pragma unroll
        for (int j = 0; j < 8; j++)
            fr[j] = vT[(qf * 8 + j) * 132 + nt * 16 + lf];
        vf[((size_t)kg * 8 + nt) * 64 + ln] = fr;
    }
}

// ---------------------------------------------------------------------------
// Kernel 2: flash attention (max-free softmax).  grid (32, AZ=16), block 256
// (4 waves), 2 blocks/CU.  Wave owns 32 q-rows (2 m-tiles); block processes
// 8 z-granules (round-9 lesson: fewer/longer block pipelines beat more/shorter
// ones — per-block prologue+tail amortize; AZ also scales partial traffic).
// K via LDS double-buffer; V direct global->regs (L1 absorbs 4-wave dup).
// Swapped QK^T + permlane32/16 swaps keep P entirely in registers (round-6/7
// derivation).  s_setprio(1) wraps both MFMA clusters (T5, m191 +4-7%).
// Round-8 lesson: NO device-scope fences in the hot path (agent fences =
// full-L2 wb/inv on gfx950 -> cross-XCD cache thrash, 119 µs attn).
// ---------------------------------------------------------------------------
__global__ __launch_bounds__(256, 2) void attn_kernel(
    const short* __restrict__ qb, const char* __restrict__ kfg,
    const char* __restrict__ vfg, _Float16* __restrict__ OA,
    float* __restrict__ lA)
{
    __shared__ __align__(16) char kv[2][8192];        // [buf][kf granule]

    const int t    = threadIdx.x;
    const int wave = t >> 6;
    const int lane = t & 63;
    const int l16  = lane & 15;
    const int quad = lane >> 4;
    const int qr0  = blockIdx.x * 128;
    const int g0   = blockIdx.y * 8;    // first z-granule (32 rows each)

    auto stage = [&](int g, int b) {
        const char* kb_ = kfg + (size_t)(g0 + g) * 8192 + wave * 2048;
        g2lds16(kb_ + lane * 16,        &kv[b][wave * 2048]);
        g2lds16(kb_ + 1024 + lane * 16, &kv[b][wave * 2048 + 1024]);
    };

    stage(0, 0);

    // q A-fragments direct from global (once; overlaps staging). 2 m-tiles.
    short8 af[2][4];
#pragma unroll
    for (int mt = 0; mt < 2; mt++) {
        const short* qrow = qb + (size_t)(qr0 + wave * 32 + mt * 16 + l16) * DA + quad * 8;
#pragma unroll
        for (int ks = 0; ks < 4; ks++)
            af[mt][ks] = *(const short8*)(qrow + ks * 32);
    }

    // constant ones B-frag (row-sum column): B[0][k] = 1
    short8 bones;
#pragma unroll
    for (int j = 0; j < 8; j++) bones[j] = (l16 == 0) ? (short)0x3F80 : (short)0;

    f32x4 O[2][9];
#pragma unroll
    for (int mt = 0; mt < 2; mt++)
#pragma unroll
        for (int i = 0; i < 9; i++) O[mt][i] = (f32x4){0.f, 0.f, 0.f, 0.f};

    __syncthreads();   // buf0 ready

#pragma unroll 1
    for (int g = 0; g < 8; g++) {
        const int b = g & 1;
        if (g + 1 < 8) stage(g + 1, b ^ 1);   // async; drains at end-of-iter barrier

        // ---- V(g) direct global->regs (issued early; consumed after softmax) ----
        const short8* vgp = (const short8*)(vfg + (size_t)(g0 + g) * 8192);
        short8 b2v[8];
#pragma unroll
        for (int nt = 0; nt < 8; nt++)
            b2v[nt] = vgp[nt * 64 + lane];

        const char* kb_ = &kv[b][0];

        // ---- S^T = k @ q^T over this 32-z granule (k-frag shared by both mt) ----
        f32x4 st[2][2];
#pragma unroll
        for (int zh = 0; zh < 2; zh++)
#pragma unroll
            for (int mt = 0; mt < 2; mt++) st[zh][mt] = (f32x4){0.f, 0.f, 0.f, 0.f};
        __builtin_amdgcn_s_setprio(1);
#pragma unroll
        for (int ks = 0; ks < 4; ks++)
#pragma unroll
            for (int zh = 0; zh < 2; zh++) {
                const short8 kfr = *(const short8*)(kb_ + ((ks * 2 + zh) * 64 + lane) * 16);
                st[zh][0] = __builtin_amdgcn_mfma_f32_16x16x32_bf16(kfr, af[0][ks], st[zh][0], 0, 0, 0);
                st[zh][1] = __builtin_amdgcn_mfma_f32_16x16x32_bf16(kfr, af[1][ks], st[zh][1], 0, 0, 0);
            }
        __builtin_amdgcn_s_setprio(0);

        // ---- in-register softmax -> PV A-frags (2 p32 + 2 p16 swaps per mt) ----
        short8 a2[2];
#pragma unroll
        for (int mt = 0; mt < 2; mt++) {
            unsigned x0 = cvt_pk_bf16(exp2f(st[0][mt][0]), exp2f(st[0][mt][1]));
            unsigned x1 = cvt_pk_bf16(exp2f(st[0][mt][2]), exp2f(st[0][mt][3]));
            unsigned y0 = cvt_pk_bf16(exp2f(st[1][mt][0]), exp2f(st[1][mt][1]));
            unsigned y1 = cvt_pk_bf16(exp2f(st[1][mt][2]), exp2f(st[1][mt][3]));
            asm volatile("v_permlane32_swap_b32 %0, %1" : "+v"(x0), "+v"(y0));
            asm volatile("v_permlane32_swap_b32 %0, %1" : "+v"(x1), "+v"(y1));
            asm volatile("v_permlane16_swap_b32 %0, %1" : "+v"(x0), "+v"(y0));
            asm volatile("v_permlane16_swap_b32 %0, %1" : "+v"(x1), "+v"(y1));
            union { short8 s; unsigned u[4]; } pa;
            pa.u[0] = x0;
            pa.u[1] = x1;
            pa.u[2] = y0;
            pa.u[3] = y1;
            a2[mt] = pa.s;
        }

        // ---- O += P @ [V | 1] (K=32, all operands in registers) ----
        __builtin_amdgcn_s_setprio(1);
#pragma unroll
        for (int nt = 0; nt < 8; nt++) {
            O[0][nt] = __builtin_amdgcn_mfma_f32_16x16x32_bf16(a2[0], b2v[nt], O[0][nt], 0, 0, 0);
            O[1][nt] = __builtin_amdgcn_mfma_f32_16x16x32_bf16(a2[1], b2v[nt], O[1][nt], 0, 0, 0);
        }
        O[0][8] = __builtin_amdgcn_mfma_f32_16x16x32_bf16(a2[0], bones, O[0][8], 0, 0, 0);
        O[1][8] = __builtin_amdgcn_mfma_f32_16x16x32_bf16(a2[1], bones, O[1][8], 0, 0, 0);
        __builtin_amdgcn_s_setprio(0);
        __syncthreads();   // staging for g+1 drained; all waves done with K buf b
    }

    // ---- per-wave partial -> global fp16 (rows wave-exclusive); l stays fp32 ----
    const int rw = qr0 + wave * 32;
    _Float16* Ob = OA + (size_t)blockIdx.y * L_SEQ * DA;
#pragma unroll
    for (int mt = 0; mt < 2; mt++)
#pragma unroll
        for (int nt = 0; nt < 8; nt++)
#pragma unroll
            for (int r = 0; r < 4; r++)
                Ob[(size_t)(rw + mt * 16 + quad * 4 + r) * DA + nt * 16 + l16] =
                    (_Float16)O[mt][nt][r];
    if (l16 == 0) {
        float* lb = lA + (size_t)blockIdx.y * L_SEQ;
#pragma unroll
        for (int mt = 0; mt < 2; mt++)
#pragma unroll
            for (int r = 0; r < 4; r++)
                lb[rw + mt * 16 + quad * 4 + r] = O[mt][8][r];
    }
}

// ---------------------------------------------------------------------------
// Kernel 3: merge AZ partials: out = sum(OA) / sum(lA).  grid 256, block 256.
// OA is fp16 (16B = 8 elems per lane-load), accumulate fp32.
// ---------------------------------------------------------------------------
__global__ __launch_bounds__(256) void merge_kernel(
    const _Float16* __restrict__ OA, const float* __restrict__ lA,
    float* __restrict__ out)
{
    const int t = threadIdx.x;
    const int row = blockIdx.x * 16 + (t >> 4);
    const int cg = (t & 15) * 8;

    float acc[8];
#pragma unroll
    for (int j = 0; j < 8; j++) acc[j] = 0.f;
    float lsum = 0.f;
#pragma unroll
    for (int zz = 0; zz < AZ; zz++) {
        const half8 v = *(const half8*)&OA[((size_t)zz * L_SEQ + row) * DA + cg];
#pragma unroll
        for (int j = 0; j < 8; j++) acc[j] += (float)v[j];
        lsum += lA[(size_t)zz * L_SEQ + row];
    }
    const float inv = 1.f / lsum;
    f32x4 o0, o1;
#pragma unroll
    for (int j = 0; j < 4; j++) { o0[j] = acc[j] * inv; o1[j] = acc[4 + j] * inv; }
    f32x4* dst = (f32x4*)&out[(size_t)row * DA + cg];
    dst[0] = o0;
    dst[1] = o1;
}

// ---------------------------------------------------------------------------
extern "C" void kernel_launch(void* const* d_in, const int* in_sizes, int n_in,
                              void* d_out, int out_size, void* d_ws, size_t ws_size,
                              hipStream_t stream) {
    (void)in_sizes; (void)n_in; (void)out_size; (void)ws_size;
    const float* x  = (const float*)d_in[0];
    const float* z  = (const float*)d_in[1];
    const float* Wq = (const float*)d_in[2];
    const float* bq = (const float*)d_in[3];
    const float* Wk = (const float*)d_in[4];
    const float* bk = (const float*)d_in[5];
    const float* Wv = (const float*)d_in[6];
    const float* bv = (const float*)d_in[7];
    float* out = (float*)d_out;

    short8*   WTf = (short8*)d_ws;
    short*    qb  = (short*)((char*)d_ws + OFF_QB);
    short8*   kf  = (short8*)((char*)d_ws + OFF_KF);
    short8*   vf  = (short8*)((char*)d_ws + OFF_VF);
    _Float16* OA  = (_Float16*)((char*)d_ws + OFF_OA);       // AZ*L*DA fp16
    float*    lA  = (float*)((char*)d_ws + OFF_OA + OA_BYTES);

    prep_w_kernel<<<dim3(32, 3), 256, 0, stream>>>(Wq, Wk, Wv, WTf);
    qkv_kernel<<<dim3(128, 2), 256, 0, stream>>>(x, z, (const char*)WTf,
                                                 bq, bk, bv, qb, kf, vf);
    attn_kernel<<<dim3(32, AZ), 256, 0, stream>>>(qb, (const char*)kf,
                                                  (const char*)vf, OA, lA);
    merge_kernel<<<256, 256, 0, stream>>>(OA, lA, out);
}